// Round 9
// baseline (414.548 us; speedup 1.0000x reference)
//
#include <hip/hip_runtime.h>
#include <hip/hip_bf16.h>

#define B_   4
#define DENC 512
#define T_   200
#define DDEC 640
#define U_   100
#define H_   640
#define V_   1025
#define VPAD 1152

typedef float f32x4 __attribute__((ext_vector_type(4)));
typedef __bf16 bf16x8 __attribute__((ext_vector_type(8)));
typedef unsigned short u16x8 __attribute__((ext_vector_type(8)));

__device__ __forceinline__ float bf2f(unsigned short s) {
    return __uint_as_float(((unsigned)s) << 16);
}

__device__ __forceinline__ unsigned addrelu_pk(unsigned e, unsigned d) {
    float elo = __uint_as_float(e << 16);
    float ehi = __uint_as_float(e & 0xffff0000u);
    float dlo = __uint_as_float(d << 16);
    float dhi = __uint_as_float(d & 0xffff0000u);
    float lo = fmaxf(elo + dlo, 0.f);
    float hi = fmaxf(ehi + dhi, 0.f);
    unsigned r;
    asm("v_cvt_pk_bf16_f32 %0, %1, %2" : "=v"(r) : "v"(lo), "v"(hi));
    return r;
}

__device__ __forceinline__ void gload_lds16(const void* g, void* l) {
    __builtin_amdgcn_global_load_lds(
        (const __attribute__((address_space(1))) unsigned int*)g,
        (__attribute__((address_space(3))) unsigned int*)l, 16, 0, 0);
}

// ---------------- K1: enc_proj[b,t,h] = bf16( sum_d enc[b,d,t]*W_enc[d,h] + b_enc[h] )
// TLP-first: thread = one (h,t); block = 64h x 4t; grid 2000 blocks (~8 waves/SIMD).
// W row load coalesced (64 lanes x 4B); enc element wave-uniform broadcast.
__global__ __launch_bounds__(256) void enc_proj_kernel(
    const float* __restrict__ enc, const float* __restrict__ W,
    const float* __restrict__ bias, __hip_bfloat16* __restrict__ out)
{
    int tid = threadIdx.x;
    int h = blockIdx.x * 64 + (tid & 63);
    int t = blockIdx.y * 4 + (tid >> 6);
    int b = blockIdx.z;
    const float* Wc = W + h;
    const float* ec = enc + (size_t)b * DENC * T_ + t;
    float acc = 0.f;
    #pragma unroll 8
    for (int d = 0; d < DENC; ++d)
        acc += Wc[(size_t)d * H_] * ec[(size_t)d * T_];
    out[((size_t)b * T_ + t) * H_ + h] = __float2bfloat16(acc + bias[h]);
}

// ---------------- K2: dec_proj[b,u,h] — same structure, 1000 blocks
__global__ __launch_bounds__(256) void dec_proj_kernel(
    const float* __restrict__ dec, const float* __restrict__ W,
    const float* __restrict__ bias, __hip_bfloat16* __restrict__ out)
{
    int tid = threadIdx.x;
    int h = blockIdx.x * 64 + (tid & 63);
    int u = blockIdx.y * 4 + (tid >> 6);
    int b = blockIdx.z;
    const float* Wc = W + h;
    const float* dc = dec + (size_t)b * DDEC * U_ + u;
    float acc = 0.f;
    #pragma unroll 8
    for (int d = 0; d < DDEC; ++d)
        acc += Wc[(size_t)d * H_] * dc[(size_t)d * U_];
    out[((size_t)b * U_ + u) * H_ + h] = __float2bfloat16(acc + bias[h]);
}

// ---------------- K3: Wt[v][h] = bf16(W_out[h][v]) (v padded to VPAD with zeros)
__global__ __launch_bounds__(256) void wt_transpose_kernel(
    const float* __restrict__ W, unsigned short* __restrict__ Wt)
{
    int hc = blockIdx.x, vc = blockIdx.y;
    int h0 = hc * 64, v0 = vc * 64;
    __shared__ float tile[64][65];
    int tid = threadIdx.x;
    #pragma unroll
    for (int it = 0; it < 16; ++it) {
        int hl = it * 4 + (tid >> 6);
        int vl = tid & 63;
        int v = v0 + vl;
        tile[hl][vl] = (v < V_) ? W[(size_t)(h0 + hl) * V_ + v] : 0.f;
    }
    __syncthreads();
    #pragma unroll
    for (int it = 0; it < 16; ++it) {
        int vl = it * 4 + (tid >> 6);
        int hl = tid & 63;
        __bf16 bv = (__bf16)tile[hl][vl];
        Wt[(size_t)(v0 + vl) * H_ + h0 + hl] = *(unsigned short*)&bv;
    }
}

// ---------------- K4: UNCHANGED round-8 joint kernel (proven: 287us, absmax 0.03125)
__global__ __launch_bounds__(256) void joint_kernel(
    const unsigned short* __restrict__ encP,   // [B,T,H] bf16
    const unsigned short* __restrict__ decP,   // [B,U,H] bf16
    const unsigned short* __restrict__ Wt,     // [VPAD][H] bf16
    const float* __restrict__ b_out,           // [V]
    float* __restrict__ out)                   // [B,T,U,V] f32
{
    __shared__ uint4 LA[2][64][4];             // 8 KB
    __shared__ uint4 LB[2][256][4];            // 32 KB

    int vi = blockIdx.x;                       // 0..3
    int tu = blockIdx.y;                       // 0..324
    int b  = blockIdx.z;
    int tt = tu / 13, ut = tu % 13;
    int t0 = tt * 8, u0 = ut * 8, vb = vi * 256;
    int tid = threadIdx.x;
    int lane = tid & 63, w = tid >> 6;         // w = wave = col-group 0..3
    int lrow = lane & 15, kg = lane >> 4;

    int r  = tid >> 2, kc = tid & 3;
    int ta = t0 + (r >> 3);
    int ua = u0 + (r & 7); if (ua > U_ - 1) ua = U_ - 1;
    const unsigned short* eR = encP + ((size_t)b * T_ + ta) * H_ + kc * 8;
    const unsigned short* dR = decP + ((size_t)b * U_ + ua) * H_ + kc * 8;
    int fA = (r >> 1) & 3;

    int pcB = lane & 3;
    const unsigned short* gB[4];
    #pragma unroll
    for (int m = 0; m < 4; ++m) {
        int cl = w * 64 + m * 16 + (lane >> 2);
        gB[m] = Wt + (size_t)(vb + cl) * H_ + (pcB ^ ((cl >> 1) & 3)) * 8;
    }

    f32x4 acc[4][4];
    #pragma unroll
    for (int i = 0; i < 4; ++i)
        #pragma unroll
        for (int j = 0; j < 4; ++j)
            acc[i][j] = (f32x4){0.f, 0.f, 0.f, 0.f};

    {
        uint4 E = *(const uint4*)(eR);
        uint4 D = *(const uint4*)(dR);
        uint4 x;
        x.x = addrelu_pk(E.x, D.x); x.y = addrelu_pk(E.y, D.y);
        x.z = addrelu_pk(E.z, D.z); x.w = addrelu_pk(E.w, D.w);
        LA[0][r][kc ^ fA] = x;
        #pragma unroll
        for (int m = 0; m < 4; ++m)
            gload_lds16(gB[m], &LB[0][w * 64 + m * 16][0]);
    }
    __syncthreads();

    #pragma unroll 2
    for (int kt = 0; kt < 20; ++kt) {
        int cur = kt & 1;
        uint4 En, Dn;
        if (kt < 19) {
            En = *(const uint4*)(eR + (kt + 1) * 32);
            Dn = *(const uint4*)(dR + (kt + 1) * 32);
            #pragma unroll
            for (int m = 0; m < 4; ++m)
                gload_lds16(gB[m] + (kt + 1) * 32, &LB[cur ^ 1][w * 64 + m * 16][0]);
        }
        bf16x8 a[4], bq[4];
        #pragma unroll
        for (int i = 0; i < 4; ++i) {
            int row = i * 16 + lrow;
            a[i] = __builtin_bit_cast(bf16x8, LA[cur][row][kg ^ ((row >> 1) & 3)]);
        }
        #pragma unroll
        for (int j = 0; j < 4; ++j) {
            int col = w * 64 + j * 16 + lrow;
            bq[j] = __builtin_bit_cast(bf16x8, LB[cur][col][kg ^ ((col >> 1) & 3)]);
        }
        #pragma unroll
        for (int i = 0; i < 4; ++i)
            #pragma unroll
            for (int j = 0; j < 4; ++j)
                acc[i][j] = __builtin_amdgcn_mfma_f32_16x16x32_bf16(a[i], bq[j], acc[i][j], 0, 0, 0);
        if (kt < 19) {
            uint4 x;
            x.x = addrelu_pk(En.x, Dn.x); x.y = addrelu_pk(En.y, Dn.y);
            x.z = addrelu_pk(En.z, Dn.z); x.w = addrelu_pk(En.w, Dn.w);
            LA[cur ^ 1][r][kc ^ fA] = x;
        }
        __syncthreads();
    }

    #pragma unroll
    for (int j = 0; j < 4; ++j) {
        int v = vb + w * 64 + j * 16 + lrow;
        float bo = b_out[v];
        #pragma unroll
        for (int i = 0; i < 4; ++i) {
            #pragma unroll
            for (int q = 0; q < 4; ++q) {
                int row = i * 16 + kg * 4 + q;
                int t = t0 + (row >> 3);
                int u = u0 + (row & 7);
                if (u < U_)
                    out[(((size_t)b * T_ + t) * U_ + u) * V_ + v] = acc[i][j][q] + bo;
            }
        }
    }
}

// ---------------- K5: last output column v=1024 (plain dot products)
__global__ __launch_bounds__(256) void lastcol_kernel(
    const unsigned short* __restrict__ encP, const unsigned short* __restrict__ decP,
    const unsigned short* __restrict__ Wt, const float* __restrict__ b_out,
    float* __restrict__ out)
{
    int idx = blockIdx.x * 256 + threadIdx.x;
    if (idx >= B_ * T_ * U_) return;
    int u = idx % U_;
    int t = (idx / U_) % T_;
    int b = idx / (U_ * T_);
    const u16x8* e = (const u16x8*)(encP + ((size_t)b * T_ + t) * H_);
    const u16x8* d = (const u16x8*)(decP + ((size_t)b * U_ + u) * H_);
    const u16x8* wv = (const u16x8*)(Wt + (size_t)1024 * H_);
    float acc = 0.f;
    for (int c = 0; c < H_ / 8; ++c) {
        u16x8 ev = e[c], dv = d[c], wq = wv[c];
        #pragma unroll
        for (int m = 0; m < 8; ++m)
            acc += fmaxf(bf2f(ev[m]) + bf2f(dv[m]), 0.f) * bf2f(wq[m]);
    }
    out[((size_t)(b * T_ + t) * U_ + u) * V_ + 1024] = acc + b_out[1024];
}

extern "C" void kernel_launch(void* const* d_in, const int* in_sizes, int n_in,
                              void* d_out, int out_size, void* d_ws, size_t ws_size,
                              hipStream_t stream) {
    const float* enc    = (const float*)d_in[0];
    const float* dec    = (const float*)d_in[1];
    const float* W_enc  = (const float*)d_in[2];
    const float* b_enc  = (const float*)d_in[3];
    const float* W_pred = (const float*)d_in[4];
    const float* b_pred = (const float*)d_in[5];
    const float* W_out  = (const float*)d_in[6];
    const float* b_out  = (const float*)d_in[7];
    float* out = (float*)d_out;

    char* ws = (char*)d_ws;
    __hip_bfloat16* encP = (__hip_bfloat16*)ws;                       // 1,024,000 B
    __hip_bfloat16* decP = (__hip_bfloat16*)(ws + 1024000);           //   512,000 B
    unsigned short* Wt   = (unsigned short*)(ws + 1024000 + 512000);  // 1,474,560 B

    enc_proj_kernel<<<dim3(10, 50, 4), 256, 0, stream>>>(enc, W_enc, b_enc, encP);
    dec_proj_kernel<<<dim3(10, 25, 4), 256, 0, stream>>>(dec, W_pred, b_pred, decP);
    wt_transpose_kernel<<<dim3(10, 18), 256, 0, stream>>>(W_out, Wt);
    joint_kernel<<<dim3(4, 325, 4), 256, 0, stream>>>(
        (const unsigned short*)encP, (const unsigned short*)decP, Wt, b_out, out);
    lastcol_kernel<<<dim3((B_ * T_ * U_ + 255) / 256), 256, 0, stream>>>(
        (const unsigned short*)encP, (const unsigned short*)decP, Wt, b_out, out);
}